// Round 26
// baseline (78.698 us; speedup 1.0000x reference)
//
#include <hip/hip_runtime.h>
#include <hip/hip_bf16.h>

typedef int   i32x4 __attribute__((ext_vector_type(4)));
typedef int   int4v __attribute__((ext_vector_type(4)));

#define N_IMG 64
#define CIN   256
#define COUT  256
#define HH    28
#define WW    28
#define PH    30
#define PW    30
#define M_TOT (N_IMG*HH*WW)          // 50176
#define OUT_ELEMS (N_IMG*COUT*HH*WW) // 12845056

// workspace layout (bytes) — all int8
#define XT_BYTES   ((size_t)N_IMG*PH*PW*CIN)       // 14745600
#define WT_OFF     (XT_BYTES)
#define WT_BYTES   ((size_t)9*COUT*CIN)            // 589824
#define BQ_OFF     (WT_OFF + WT_BYTES)             // 15335424

#define GLD16(g, l) __builtin_amdgcn_global_load_lds( \
    (const __attribute__((address_space(1))) void*)(g), \
    (__attribute__((address_space(3))) void*)(l), 16, 0, 0)

// ---------------------------------------------------------------------------
// Kernel 1 (merged prep, R20/R24 measured-best variant): blocks 0..1919 = x
// transform (one padded row each); 1920..2175 = w quant.
__global__ __launch_bounds__(256) void prep(const int* __restrict__ xq,
                                            const float* __restrict__ weight,
                                            const float* __restrict__ scale_x,
                                            const float* __restrict__ bias,
                                            signed char* __restrict__ xt,
                                            signed char* __restrict__ wt,
                                            int* __restrict__ bq,
                                            float* __restrict__ out_tail) {
    __shared__ int xs[28*260];               // [w][ci] stride 260 (16B rows)
    const int b = blockIdx.x;
    const int t = threadIdx.x;

    if (b < N_IMG*PH) {                      // ---- transform part
        const int n = b / PH, py = b % PH;
        signed char* dst = xt + ((size_t)(n*PH + py))*PW*CIN;
        if (py == 0 || py == PH-1) {
            int* d4 = (int*)dst;
            for (int i = t; i < PW*CIN/4; i += 256) d4[i] = 0x81818181; // -127
            return;
        }
        const int h = py - 1;
        const int* src = xq + (size_t)n*CIN*HH*WW + h*WW;
        for (int i = t; i < CIN*7; i += 256) {           // coalesced int4 loads
            const int ci = i / 7, q = i % 7;
            const int4v v = *(const int4v*)(src + ci*HH*WW + q*4);
            xs[(4*q    )*260 + ci] = v.x;                // transposed scatter
            xs[(4*q + 1)*260 + ci] = v.y;
            xs[(4*q + 2)*260 + ci] = v.z;
            xs[(4*q + 3)*260 + ci] = v.w;
        }
        __syncthreads();
        for (int i = t; i < PW*CIN/4; i += 256) {        // pack + uchar4 store
            const int px = i >> 6, ci0 = (i & 63) << 2;
            unsigned int o;
            if (px == 0 || px == PW-1) o = 0x81818181u;
            else {
                const int4v v = *(const int4v*)&xs[(px - 1)*260 + ci0]; // b128, CF
                const unsigned int b0 = (unsigned char)(v.x - 127);
                const unsigned int b1 = (unsigned char)(v.y - 127);
                const unsigned int b2 = (unsigned char)(v.z - 127);
                const unsigned int b3 = (unsigned char)(v.w - 127);
                o = b0 | (b1 << 8) | (b2 << 16) | (b3 << 24);
            }
            ((unsigned int*)dst)[i] = o;
        }
        return;
    }

    // ---- quant part (co = b - 1920)
    float* red  = (float*)xs;                // reuse LDS
    int*   sred = (int*)xs + 256;
    const int co = b - N_IMG*PH;
    const float* wrow = weight + (size_t)co*CIN*9;
    float wv[9];
    float mx = 0.f;
    for (int it = 0; it < 9; ++it) {
        float v = wrow[it*256 + t];
        wv[it] = v;
        mx = fmaxf(mx, fabsf(v));
    }
    red[t] = mx;
    __syncthreads();
    for (int s = 128; s > 0; s >>= 1) {
        if (t < s) red[t] = fmaxf(red[t], red[t+s]);
        __syncthreads();
    }
    const float scale = fmaxf(red[0], 1e-8f) / 127.f;
    int isum = 0;
    for (int it = 0; it < 9; ++it) {
        const int i = it*256 + t;            // index over [ci][r][s]
        const int ci = i / 9, rs = i % 9;
        float q = rintf(wv[it] / scale);     // rintf = round-half-even = jnp.round
        q = fminf(fmaxf(q, -128.f), 127.f);
        const int qi = (int)q;
        isum += qi;
        wt[(size_t)rs*COUT*CIN + co*CIN + ci] = (signed char)qi;
    }
    sred[t] = isum;
    __syncthreads();
    for (int s = 128; s > 0; s >>= 1) {
        if (t < s) sred[t] += sred[t+s];
        __syncthreads();
    }
    if (t == 0) {
        const float so = scale * scale_x[0];
        out_tail[co] = so;
        bq[co] = (int)rintf(bias[co] / so) + 127 * sred[0];
    }
}

// ---------------------------------------------------------------------------
// Kernel 2: implicit-GEMM conv, int8 MFMA — REGIME-GATED retry of counted-
// vmcnt pipelining (R7/R8/R10 all ran under the scattered-staging TA floor,
// where latency-hiding cannot show; post-R15 the stall IS the drain latency).
// BM=128 x BN=128 x BK=64, 256 thr / 4 waves (2co x 2m), per-wave 64x64
// acc[4][4]; per tile: 16 MFMA + 8 ds_read_b128/wave; 36 K-tiles.
// LDS: THREE buffers x (A 8KB + B 8KB) = 48KB -> still 2 blocks/CU.
// Pipeline depth 2: STAGE(t+2) each phase; GATE = s_waitcnt vmcnt(4)
// (tile-to-compute's 4 loads/thread, issued 2 phases (~500+cy) earlier,
// retired; next tile's 4 stay in flight — never 0 in the main loop) +
// s_barrier.  Staging = R15 pattern at 64B rows: 4 lanes x 16B coalesced
// runs, pre-swizzled source chunk skc=(d&3)^(srow&3), linear LDS dest,
// XOR-swizzled ds_read (chunk = kg^(lr&3)); full-wave bank tally = exactly
// 8 accesses/bank = the b128 floor, conflict-free.
// Bijective XCD swizzle (392 = 8x49).  Grid (392, 2).
__global__ __launch_bounds__(256, 2) void conv_mfma(const signed char* __restrict__ xt,
                                                    const signed char* __restrict__ wt,
                                                    const int* __restrict__ bq,
                                                    float* __restrict__ out) {
    __shared__ signed char Ash[3*8192];   // [buf][row128][64B] XOR-swizzled
    __shared__ signed char Bsh[3*8192];
    const int d = threadIdx.x;
    const int lane = d & 63, lr = lane & 15, kg = lane >> 4;
    const int w4 = d >> 6;
    const int wm = w4 >> 1, wn = w4 & 1;     // wave grid: 2 (co) x 2 (m)
    const int bx = blockIdx.x;               // 0..391
    const int mb = (bx & 7)*49 + (bx >> 3);  // bijective XCD swizzle (392=8*49)
    const int m0 = mb << 7;
    const int co0 = blockIdx.y << 7;

    // staging: 4 lanes/row x 16B = 64B run; rows srow, srow+64 per operand.
    const int srow = d >> 2;                 // 0..63
    const int skc  = (d & 3) ^ (srow & 3);
    const signed char* aS = wt + (size_t)(co0 + srow)*CIN + (skc << 4);
    const signed char* bS0;
    const signed char* bS1;
    {
        int m = m0 + srow;
        int n = m / 784, hw = m % 784, h = hw / 28, wq = hw % 28;
        bS0 = xt + ((size_t)((n*PH + h)*PW + wq))*CIN + (skc << 4);
        m += 64;
        n = m / 784; hw = m % 784; h = hw / 28; wq = hw % 28;
        bS1 = xt + ((size_t)((n*PH + h)*PW + wq))*CIN + (skc << 4);
    }
    const int d16 = d << 4;                  // linear LDS dest (bytes)

    i32x4 acc[4][4] = {};

    // frag read byte bases: row*64 + swizzled 16B chunk (kg ^ (lr&3))
    const int arb = (wm*64 + lr)*64 + ((kg ^ (lr & 3)) << 4);
    const int brb = (wn*64 + lr)*64 + ((kg ^ (lr & 3)) << 4);

#define STAGE(T_, P_) do { \
    const int tap_ = (T_) >> 2, c_ = (T_) & 3; \
    const int r3_ = (tap_*171) >> 9; \
    const int ao_ = tap_*(COUT*CIN) + (c_ << 6); \
    const int bo_ = ((r3_*PW + (tap_ - r3_*3)) << 8) + (c_ << 6); \
    GLD16(aS + ao_,             Ash + (P_)*8192 +        d16); \
    GLD16(aS + ao_ + 64*CIN,    Ash + (P_)*8192 + 4096 + d16); \
    GLD16(bS0 + bo_,            Bsh + (P_)*8192 +        d16); \
    GLD16(bS1 + bo_,            Bsh + (P_)*8192 + 4096 + d16); \
} while (0)

#define COMPUTE(P_) do { \
    const signed char* A_ = Ash + (P_)*8192; \
    const signed char* B_ = Bsh + (P_)*8192; \
    i32x4 af[4], bf[4]; \
    _Pragma("unroll") \
    for (int mr = 0; mr < 4; ++mr) af[mr] = *(const i32x4*)&A_[arb + mr*1024]; \
    _Pragma("unroll") \
    for (int nr = 0; nr < 4; ++nr) bf[nr] = *(const i32x4*)&B_[brb + nr*1024]; \
    _Pragma("unroll") \
    for (int mr = 0; mr < 4; ++mr) \
        _Pragma("unroll") \
        for (int nr = 0; nr < 4; ++nr) \
            acc[mr][nr] = __builtin_amdgcn_mfma_i32_16x16x64_i8( \
                af[mr], bf[nr], acc[mr][nr], 0, 0, 0); \
} while (0)

#define GATE(N_) do { \
    asm volatile("s_waitcnt vmcnt(" #N_ ")" ::: "memory"); \
    __builtin_amdgcn_s_barrier(); \
    __builtin_amdgcn_sched_barrier(0); \
} while (0)

    STAGE(0, 0);
    STAGE(1, 1);
#pragma unroll 1
    for (int tt = 0; tt < 33; tt += 3) {     // tiles 0..32; stages thru 34
        GATE(4); STAGE(tt + 2, 2); COMPUTE(0);
        GATE(4); STAGE(tt + 3, 0); COMPUTE(1);
        GATE(4); STAGE(tt + 4, 1); COMPUTE(2);
    }
    GATE(4); STAGE(35, 2); COMPUTE(0);       // tile 33
    GATE(4); COMPUTE(1);                     // tile 34 (35's loads in flight)
    GATE(0); COMPUTE(2);                     // tile 35

    // epilogue: D row = co (kg*4+rg), col = m (lr); 64B coalesced runs
#pragma unroll
    for (int nr = 0; nr < 4; ++nr) {
        const int mm = m0 + wn*64 + nr*16 + lr;
        const int nn = mm / 784, hw2 = mm % 784;
        float* orow = out + (size_t)nn*COUT*784 + hw2;
#pragma unroll
        for (int mr = 0; mr < 4; ++mr) {
            const int co = co0 + wm*64 + mr*16 + kg*4;
#pragma unroll
            for (int rg = 0; rg < 4; ++rg)
                orow[(size_t)(co + rg)*784] = (float)(acc[mr][nr][rg] + bq[co + rg]);
        }
    }
#undef STAGE
#undef COMPUTE
#undef GATE
}

// ---------------------------------------------------------------------------
extern "C" void kernel_launch(void* const* d_in, const int* in_sizes, int n_in,
                              void* d_out, int out_size, void* d_ws, size_t ws_size,
                              hipStream_t stream) {
    const int*   xq      = (const int*)d_in[0];
    const float* scale_x = (const float*)d_in[1];
    const float* weight  = (const float*)d_in[2];
    const float* bias    = (const float*)d_in[3];
    float* out = (float*)d_out;

    signed char* xt = (signed char*)d_ws;
    signed char* wt = (signed char*)((char*)d_ws + WT_OFF);
    int*         bq = (int*)((char*)d_ws + BQ_OFF);

    hipLaunchKernelGGL(prep, dim3(N_IMG*PH + COUT), dim3(256), 0, stream,
                       xq, weight, scale_x, bias, xt, wt, bq, out + OUT_ELEMS);
    hipLaunchKernelGGL(conv_mfma, dim3(M_TOT/128, COUT/128), dim3(256), 0, stream,
                       xt, wt, bq, out);
}

// Round 27
// 67.131 us; speedup vs baseline: 1.1723x; 1.1723x over previous
//
#include <hip/hip_runtime.h>
#include <hip/hip_bf16.h>

typedef int   i32x4 __attribute__((ext_vector_type(4)));
typedef int   int4v __attribute__((ext_vector_type(4)));

#define N_IMG 64
#define CIN   256
#define COUT  256
#define HH    28
#define WW    28
#define PH    30
#define PW    30
#define M_TOT (N_IMG*HH*WW)          // 50176
#define OUT_ELEMS (N_IMG*COUT*HH*WW) // 12845056

// workspace layout (bytes) — all int8
#define XT_BYTES   ((size_t)N_IMG*PH*PW*CIN)       // 14745600
#define WT_OFF     (XT_BYTES)
#define WT_BYTES   ((size_t)9*COUT*CIN)            // 589824
#define BQ_OFF     (WT_OFF + WT_BYTES)             // 15335424

#define GLD16(g, l) __builtin_amdgcn_global_load_lds( \
    (const __attribute__((address_space(1))) void*)(g), \
    (__attribute__((address_space(3))) void*)(l), 16, 0, 0)

// ---------------------------------------------------------------------------
// Kernel 1 (merged prep, measured-best R20 variant): blocks 0..1919 = x
// transform (one padded row each); 1920..2175 = w quant.
//  Transform: x int32 NCHW -> padded int8 NHWC [N][30][30][256], value x-127,
//  PAD = -127 (conv_i8 + 127*sum(w) == true zero-padded conv).
//  LDS TRANSPOSED [w][ci] stride 260 ints (1040B = 65*16, 16B-aligned rows):
//  pack phase reads 4 consecutive ci as one aligned conflict-free ds_read_b128.
//  Quant: per-co symmetric int8 weight quant; bq folds bias + 127*sum(w_q).
__global__ __launch_bounds__(256) void prep(const int* __restrict__ xq,
                                            const float* __restrict__ weight,
                                            const float* __restrict__ scale_x,
                                            const float* __restrict__ bias,
                                            signed char* __restrict__ xt,
                                            signed char* __restrict__ wt,
                                            int* __restrict__ bq,
                                            float* __restrict__ out_tail) {
    __shared__ int xs[28*260];               // [w][ci] stride 260
    const int b = blockIdx.x;
    const int t = threadIdx.x;

    if (b < N_IMG*PH) {                      // ---- transform part
        const int n = b / PH, py = b % PH;
        signed char* dst = xt + ((size_t)(n*PH + py))*PW*CIN;
        if (py == 0 || py == PH-1) {
            int* d4 = (int*)dst;
            for (int i = t; i < PW*CIN/4; i += 256) d4[i] = 0x81818181; // -127
            return;
        }
        const int h = py - 1;
        const int* src = xq + (size_t)n*CIN*HH*WW + h*WW;
        for (int i = t; i < CIN*7; i += 256) {           // coalesced int4 loads
            const int ci = i / 7, q = i % 7;
            const int4v v = *(const int4v*)(src + ci*HH*WW + q*4);
            xs[(4*q    )*260 + ci] = v.x;                // transposed scatter
            xs[(4*q + 1)*260 + ci] = v.y;
            xs[(4*q + 2)*260 + ci] = v.z;
            xs[(4*q + 3)*260 + ci] = v.w;
        }
        __syncthreads();
        for (int i = t; i < PW*CIN/4; i += 256) {        // pack + uchar4 store
            const int px = i >> 6, ci0 = (i & 63) << 2;
            unsigned int o;
            if (px == 0 || px == PW-1) o = 0x81818181u;
            else {
                const int4v v = *(const int4v*)&xs[(px - 1)*260 + ci0]; // b128, CF
                const unsigned int b0 = (unsigned char)(v.x - 127);
                const unsigned int b1 = (unsigned char)(v.y - 127);
                const unsigned int b2 = (unsigned char)(v.z - 127);
                const unsigned int b3 = (unsigned char)(v.w - 127);
                o = b0 | (b1 << 8) | (b2 << 16) | (b3 << 24);
            }
            ((unsigned int*)dst)[i] = o;
        }
        return;
    }

    // ---- quant part (co = b - 1920)
    float* red  = (float*)xs;                // reuse LDS
    int*   sred = (int*)xs + 256;
    const int co = b - N_IMG*PH;
    const float* wrow = weight + (size_t)co*CIN*9;
    float wv[9];
    float mx = 0.f;
    for (int it = 0; it < 9; ++it) {
        float v = wrow[it*256 + t];
        wv[it] = v;
        mx = fmaxf(mx, fabsf(v));
    }
    red[t] = mx;
    __syncthreads();
    for (int s = 128; s > 0; s >>= 1) {
        if (t < s) red[t] = fmaxf(red[t], red[t+s]);
        __syncthreads();
    }
    const float scale = fmaxf(red[0], 1e-8f) / 127.f;
    int isum = 0;
    for (int it = 0; it < 9; ++it) {
        const int i = it*256 + t;            // index over [ci][r][s]
        const int ci = i / 9, rs = i % 9;
        float q = rintf(wv[it] / scale);     // rintf = round-half-even = jnp.round
        q = fminf(fmaxf(q, -128.f), 127.f);
        const int qi = (int)q;
        isum += qi;
        wt[(size_t)rs*COUT*CIN + co*CIN + ci] = (signed char)qi;
    }
    sred[t] = isum;
    __syncthreads();
    for (int s = 128; s > 0; s >>= 1) {
        if (t < s) sred[t] += sred[t+s];
        __syncthreads();
    }
    if (t == 0) {
        const float so = scale * scale_x[0];
        out_tail[co] = so;
        bq[co] = (int)rintf(bias[co] / so) + 127 * sred[0];
    }
}

// ---------------------------------------------------------------------------
// Kernel 2: implicit-GEMM conv — the measured-best R16/R17/R18/R20 winner.
// int8 MFMA (exact i32 accumulation; x shifted by -127 with PAD=-127 and
// bias-folded correction), coalesced 128B staging runs, pre-swizzled global
// source -> linear LDS dest -> XOR-swizzled ds_read (rule #21), 2 blocks/CU.
// BM=128 x BN=128 x BK=128, 256 thr / 4 waves (2co x 2m), per-wave 64x64
// acc[4][4], 32 MFMA + 16 ds_read_b128 per tile, 18 K-tiles, LDS 64KB.
// Schedule = R6/R9 2-phase (4 pipelining variants and both occupancy
// directions measured worse; this is the structural plateau at ~48.5us,
// MfmaUtil ~24%).  Bijective XCD swizzle (392 = 8x49).
__global__ __launch_bounds__(256, 2) void conv_mfma(const signed char* __restrict__ xt,
                                                    const signed char* __restrict__ wt,
                                                    const int* __restrict__ bq,
                                                    float* __restrict__ out) {
    __shared__ signed char Ash[2*16384];  // [buf][row128][128B] XOR-swizzled
    __shared__ signed char Bsh[2*16384];
    const int d = threadIdx.x;
    const int w4 = d >> 6;                   // wave id 0..3
    const int lane = d & 63, lr = lane & 15, kg = lane >> 4;
    const int wm = w4 >> 1, wn = w4 & 1;     // wave grid: 2 (co) x 2 (m)
    const int bx = blockIdx.x;               // 0..391
    const int mb = (bx & 7)*49 + (bx >> 3);  // bijective XCD swizzle (392=8*49)
    const int m0 = mb << 7;
    const int co0 = blockIdx.y << 7;

    // coalesced + pre-swizzled staging: 8 lanes/row x 16B = 128B run.
    const int srow = d >> 3;                 // 0..31
    const int skc  = (d & 7) ^ (srow & 7);
    const signed char* aS = wt + (size_t)(co0 + srow)*CIN + (skc << 4); // +j*32*CIN
    const signed char* bS[4];
#pragma unroll
    for (int j = 0; j < 4; ++j) {
        const int m = m0 + srow + j*32;
        const int n = m / 784, hw = m % 784, h = hw / 28, wq = hw % 28;
        bS[j] = xt + ((size_t)((n*PH + h)*PW + wq))*CIN + (skc << 4);
    }
    const int w4off = w4 << 10;              // wave-uniform LDS base (bytes)

    i32x4 acc[4][4] = {};

    // frag read byte bases (XOR-swizzled); ks=1 flips bit 6
    const int a0 = (wm*64 + lr)*128 + ((kg ^ (lr & 7)) << 4);
    const int b0 = (wn*64 + lr)*128 + ((kg ^ (lr & 7)) << 4);

#define STAGE(T_, P_) do { \
    const int tap_ = (T_) >> 1, c_ = (T_) & 1; \
    const int r3_ = (tap_*171) >> 9; \
    const int ao_ = tap_*(COUT*CIN) + (c_ << 7); \
    const int bo_ = ((r3_*PW + (tap_ - r3_*3)) << 8) + (c_ << 7); \
    GLD16(aS + ao_,         Ash + (P_)*16384 +         w4off); \
    GLD16(aS + ao_ +  8192, Ash + (P_)*16384 +  4096 + w4off); \
    GLD16(aS + ao_ + 16384, Ash + (P_)*16384 +  8192 + w4off); \
    GLD16(aS + ao_ + 24576, Ash + (P_)*16384 + 12288 + w4off); \
    GLD16(bS[0] + bo_,      Bsh + (P_)*16384 +         w4off); \
    GLD16(bS[1] + bo_,      Bsh + (P_)*16384 +  4096 + w4off); \
    GLD16(bS[2] + bo_,      Bsh + (P_)*16384 +  8192 + w4off); \
    GLD16(bS[3] + bo_,      Bsh + (P_)*16384 + 12288 + w4off); \
} while (0)

#define COMPUTE(P_) do { \
    const signed char* A_ = Ash + (P_)*16384; \
    const signed char* B_ = Bsh + (P_)*16384; \
    _Pragma("unroll") \
    for (int ks = 0; ks < 2; ++ks) { \
        const int ar = a0 ^ (ks << 6); \
        const int br = b0 ^ (ks << 6); \
        i32x4 af[4], bf[4]; \
        _Pragma("unroll") \
        for (int mr = 0; mr < 4; ++mr) \
            af[mr] = *(const i32x4*)&A_[ar + mr*2048]; \
        _Pragma("unroll") \
        for (int nr = 0; nr < 4; ++nr) \
            bf[nr] = *(const i32x4*)&B_[br + nr*2048]; \
        _Pragma("unroll") \
        for (int mr = 0; mr < 4; ++mr) \
            _Pragma("unroll") \
            for (int nr = 0; nr < 4; ++nr) \
                acc[mr][nr] = __builtin_amdgcn_mfma_i32_16x16x64_i8( \
                    af[mr], bf[nr], acc[mr][nr], 0, 0, 0); \
    } \
} while (0)

#define SYNCPT() do { \
    asm volatile("s_waitcnt vmcnt(0) lgkmcnt(0)" ::: "memory"); \
    __builtin_amdgcn_s_barrier(); \
    __builtin_amdgcn_sched_barrier(0); \
} while (0)

    STAGE(0, 0);
#pragma unroll 1
    for (int tt = 0; tt < 18; tt += 2) {
        SYNCPT();                       // tile tt landed
        STAGE(tt + 1, 1);               // prefetch next into spare buffer
        COMPUTE(0);                     // tile tt
        SYNCPT();                       // tile tt+1 landed
        if (tt < 16) STAGE(tt + 2, 0);
        COMPUTE(1);                     // tile tt+1
    }

    // epilogue: D row = co (kg*4+rg), col = m (lr); 64B coalesced runs
#pragma unroll
    for (int nr = 0; nr < 4; ++nr) {
        const int mm = m0 + wn*64 + nr*16 + lr;
        const int nn = mm / 784, hw2 = mm % 784;
        float* orow = out + (size_t)nn*COUT*784 + hw2;
#pragma unroll
        for (int mr = 0; mr < 4; ++mr) {
            const int co = co0 + wm*64 + mr*16 + kg*4;
#pragma unroll
            for (int rg = 0; rg < 4; ++rg)
                orow[(size_t)(co + rg)*784] = (float)(acc[mr][nr][rg] + bq[co + rg]);
        }
    }
#undef STAGE
#undef COMPUTE
#undef SYNCPT
}

// ---------------------------------------------------------------------------
extern "C" void kernel_launch(void* const* d_in, const int* in_sizes, int n_in,
                              void* d_out, int out_size, void* d_ws, size_t ws_size,
                              hipStream_t stream) {
    const int*   xq      = (const int*)d_in[0];
    const float* scale_x = (const float*)d_in[1];
    const float* weight  = (const float*)d_in[2];
    const float* bias    = (const float*)d_in[3];
    float* out = (float*)d_out;

    signed char* xt = (signed char*)d_ws;
    signed char* wt = (signed char*)((char*)d_ws + WT_OFF);
    int*         bq = (int*)((char*)d_ws + BQ_OFF);

    hipLaunchKernelGGL(prep, dim3(N_IMG*PH + COUT), dim3(256), 0, stream,
                       xq, weight, scale_x, bias, xt, wt, bq, out + OUT_ELEMS);
    hipLaunchKernelGGL(conv_mfma, dim3(M_TOT/128, COUT/128), dim3(256), 0, stream,
                       xt, wt, bq, out);
}